// Round 6
// baseline (873.958 us; speedup 1.0000x reference)
//
#include <hip/hip_runtime.h>
#include <math.h>

#define EPS 1e-6f

// ws layout (floats):
//   h0     @ 0      [2][1024]  base hidden (residual base, written once by init)
//   qkv    @ 2048   5 x [2][3072]                          ends 32768
//   sync   @ 32768  ints: queues 21x16 @0, done 20x256 @1024; 6144 ints, ends 38912
//   hp     @ 38912  2 partial-h x [2][1024]                ends 43008
//   gu     @ 43008  5 x [2][2][4096]                       ends 124928
#define SYNC_OFF 32768
#define HP_OFF   38912

// Coherence-point load (agent scope): always fresh across XCDs.
__device__ __forceinline__ float ato(const float* p) {
    return __hip_atomic_load(p, __ATOMIC_RELAXED, __HIP_MEMORY_SCOPE_AGENT);
}

__device__ __forceinline__ float red32(float v) {
#pragma unroll
    for (int m = 16; m >= 1; m >>= 1) v += __shfl_xor(v, m, 64);
    return v;
}

// Consumer: wave 0 polls the 16 done-sub-counters of phase widx in parallel.
__device__ __forceinline__ void spin_wait(int* sync, int widx, int need, int t) {
    if (t < 64) {
        int* base = sync + 1024 + widx * 256;
        while (true) {
            int v = (t < 16) ? __hip_atomic_load(base + t * 16, __ATOMIC_RELAXED,
                                                 __HIP_MEMORY_SCOPE_AGENT) : 0;
#pragma unroll
            for (int m = 8; m >= 1; m >>= 1) v += __shfl_xor(v, m, 64);
            v = __shfl(v, 0, 64);
            if (v >= need) break;
            __builtin_amdgcn_s_sleep(1);
        }
    }
    __syncthreads();
}

// Producer: drain output atomics, block barrier, bump this block's sub-counter.
__device__ __forceinline__ void task_done(int* sync, int p, int t) {
    asm volatile("s_waitcnt vmcnt(0)" ::: "memory");
    __syncthreads();
    if (t == 0)
        __hip_atomic_fetch_add(sync + 1024 + p * 256 + (blockIdx.x & 15) * 16, 1,
                               __ATOMIC_RELAXED, __HIP_MEMORY_SCOPE_AGENT);
}

// ---------------- init: zero accumulators + sync + hp, build h0 ----------------
__global__ void init_kernel(const float* __restrict__ past_hidden,
                            const float* __restrict__ codec_emb,
                            const int* __restrict__ tok,
                            float* __restrict__ ws,
                            float* __restrict__ logits)
{
    size_t idx = (size_t)blockIdx.x * blockDim.x + threadIdx.x;
    size_t stride = (size_t)gridDim.x * blockDim.x;
    for (size_t i = idx; i < 30720; i += stride) ws[2048 + i] = 0.f;   // qkv x5
    for (size_t i = idx; i < 81920; i += stride) ws[43008 + i] = 0.f;  // gu x5
    for (size_t i = idx; i < 30720; i += stride) logits[i] = 0.f;
    for (size_t i = idx; i < 4096;  i += stride) ws[HP_OFF + i] = 0.f; // hp x2
    int* sync = (int*)(ws + SYNC_OFF);
    for (size_t i = idx; i < 6144; i += stride) sync[i] = 0;
    int t = tok[0];
    for (size_t i = idx; i < 1024; i += stride) {
        ws[i]        = past_hidden[i];
        ws[1024 + i] = codec_emb[(size_t)t * 1024 + i];
    }
}

// ---------------- split-K GEMV phase, deferred RMSNorm, work-stealing ----------------
// x = hbuf (+ hp0 + hp1 if hp); out[z][s][Nslice] += rsqrt(mean(x^2)+eps) * ((x*nw) @ W)
template <int S, int R>
__device__ void phase_gemv(
    float* smem, int t,
    const float* hbuf, const float* hp,   // hp nullable (partial-h gather)
    const float* __restrict__ nw,
    const float* __restrict__ W0, const float* __restrict__ W1,
    const float* __restrict__ W2, size_t w_zstride,
    float* __restrict__ out, int out_sstride, size_t out_zstride, int N,
    int nx, int ny, int nz,
    int* sync, int phase, int widx, int wneed, int didx)
{
    __shared__ int tsk;
    float* xs = smem;                 // S*1024, reused as reduction scratch
    float* sstot = smem + S * 1024;   // S*4
    const int lane = t & 63;
    const int dp = t >> 6;
    const int ntask = nx * ny * nz;
    bool waited = (widx < 0);

    while (true) {
        if (t == 0)
            tsk = __hip_atomic_fetch_add(sync + phase * 16, 1, __ATOMIC_RELAXED,
                                         __HIP_MEMORY_SCOPE_AGENT);
        __syncthreads();
        const int task = tsk;
        if (task >= ntask) break;

        const int z = task / (nx * ny);
        const int rem = task - z * (nx * ny);
        const int by = rem / nx;
        const int bx = rem - by * nx;

        const float* W;
        if (W1) W = (z == 0) ? W0 : ((z == 1) ? W1 : W2);
        else    W = W0 + (size_t)z * w_zstride;
        float* outz = out + (size_t)z * out_zstride;

        const int j = bx * 256 + lane * 4;
        const int d0 = by * (4 * R) + dp * R;

        // 1) issue weight prefetch BEFORE waiting on the dependency
        float4 wreg[R];
        const float* Wp = W + (size_t)d0 * N + j;
#pragma unroll
        for (int i = 0; i < R; ++i)
            wreg[i] = *reinterpret_cast<const float4*>(Wp + (size_t)i * N);

        if (!waited) { spin_wait(sync, widx, wneed, t); waited = true; }

        // 2) gather x at the coherence point (base + partials), apply nw
        float ss[S];
        {
            float4 nw4 = *reinterpret_cast<const float4*>(nw + t * 4);
#pragma unroll
            for (int s = 0; s < S; ++s) {
                int base = s * 1024 + t * 4;
                float x0 = ato(hbuf + base + 0);
                float x1 = ato(hbuf + base + 1);
                float x2 = ato(hbuf + base + 2);
                float x3 = ato(hbuf + base + 3);
                if (hp) {
                    x0 += ato(hp + base + 0) + ato(hp + 2048 + base + 0);
                    x1 += ato(hp + base + 1) + ato(hp + 2048 + base + 1);
                    x2 += ato(hp + base + 2) + ato(hp + 2048 + base + 2);
                    x3 += ato(hp + base + 3) + ato(hp + 2048 + base + 3);
                }
                ss[s] = x0 * x0 + x1 * x1 + x2 * x2 + x3 * x3;
                xs[base + 0] = x0 * nw4.x;
                xs[base + 1] = x1 * nw4.y;
                xs[base + 2] = x2 * nw4.z;
                xs[base + 3] = x3 * nw4.w;
            }
        }
        __syncthreads();

        // 3) dot product
        float acc[S][4];
#pragma unroll
        for (int s = 0; s < S; ++s) { acc[s][0] = acc[s][1] = acc[s][2] = acc[s][3] = 0.f; }
#pragma unroll
        for (int i = 0; i < R; ++i) {
            int dd = d0 + i;
#pragma unroll
            for (int s = 0; s < S; ++s) {
                float xv = xs[s * 1024 + dd];
                acc[s][0] += xv * wreg[i].x; acc[s][1] += xv * wreg[i].y;
                acc[s][2] += xv * wreg[i].z; acc[s][3] += xv * wreg[i].w;
            }
        }

        // 4) finish rmsnorm sum (shuffle only)
#pragma unroll
        for (int s = 0; s < S; ++s) {
            float v = ss[s];
#pragma unroll
            for (int m = 32; m >= 1; m >>= 1) v += __shfl_xor(v, m, 64);
            if (lane == 0) sstot[s * 4 + dp] = v;
        }
        __syncthreads();
        float sc[S];
#pragma unroll
        for (int s = 0; s < S; ++s) {
            float tot = sstot[s * 4 + 0] + sstot[s * 4 + 1] + sstot[s * 4 + 2] + sstot[s * 4 + 3];
            sc[s] = rsqrtf(tot / 1024.f + EPS);
        }

        // 5) cross-dp reduce + atomic add
#pragma unroll
        for (int s = 0; s < S; ++s)
#pragma unroll
            for (int c = 0; c < 4; ++c)
                xs[(dp * S + s) * 256 + lane * 4 + c] = acc[s][c] * sc[s];
        __syncthreads();
        for (int o = t; o < S * 256; o += 256) {
            int s = o >> 8;
            int col = o & 255;
            float sum = 0.f;
#pragma unroll
            for (int p = 0; p < 4; ++p) sum += xs[(p * S + s) * 256 + col];
            atomicAdd(outz + (size_t)s * out_sstride + bx * 256 + col, sum);
        }
        if (didx >= 0) task_done(sync, didx, t);
        else __syncthreads();
    }
}

// ---------------- fused attention + O-projection (128 tasks, 32 rows each) ----------------
__device__ void phase_attn_o(
    float* smem, int t,
    const float* __restrict__ qkv, const float* __restrict__ qnw,
    const float* __restrict__ knw, const float* __restrict__ W,
    float* __restrict__ hp,          // partial-h buffers (2 x [2][1024])
    float* __restrict__ kvc,
    int* sync, int phase, int widx, int wneed, int didx)
{
    __shared__ int tsk;
    float* xs = smem;                // 2048
    const int lane = t & 63;
    const int dp = t >> 6;
    bool waited = false;

    while (true) {
        if (t == 0)
            tsk = __hip_atomic_fetch_add(sync + phase * 16, 1, __ATOMIC_RELAXED,
                                         __HIP_MEMORY_SCOPE_AGENT);
        __syncthreads();
        const int task = tsk;
        if (task >= 128) break;

        const int bx = task & 3;
        const int by = task >> 2;      // 32 y-slices of 32 rows
        const int j = bx * 256 + lane * 4;
        const int d0 = by * 32 + dp * 8;
        float* out = hp + (by & 1) * 2048;

        float4 wreg[8];
        const float* Wp = W + (size_t)d0 * 1024 + j;
#pragma unroll
        for (int i = 0; i < 8; ++i)
            wreg[i] = *reinterpret_cast<const float4*>(Wp + (size_t)i * 1024);

        if (!waited) { spin_wait(sync, widx, wneed, t); waited = true; }

        const int hh = t >> 5;
        const int g = t & 31;
        float q[2][4], k[2][4], v[2][4];
#pragma unroll
        for (int s = 0; s < 2; ++s)
#pragma unroll
            for (int c = 0; c < 4; ++c) {
                int d = g + c * 32;
                q[s][c] = ato(qkv + s * 3072 +        hh * 128 + d);
                k[s][c] = ato(qkv + s * 3072 + 1024 + hh * 128 + d);
                v[s][c] = ato(qkv + s * 3072 + 2048 + hh * 128 + d);
            }
#pragma unroll
        for (int s = 0; s < 2; ++s) {
            float sq = q[s][0]*q[s][0] + q[s][1]*q[s][1] + q[s][2]*q[s][2] + q[s][3]*q[s][3];
            float sk = k[s][0]*k[s][0] + k[s][1]*k[s][1] + k[s][2]*k[s][2] + k[s][3]*k[s][3];
            sq = red32(sq); sk = red32(sk);
            float qsc = rsqrtf(sq / 128.f + EPS);
            float ksc = rsqrtf(sk / 128.f + EPS);
#pragma unroll
            for (int c = 0; c < 4; ++c) {
                q[s][c] *= qsc * qnw[g + c * 32];
                k[s][c] *= ksc * knw[g + c * 32];
            }
        }
        float inv0 = powf(10000.f, -(float)g / 64.f);
        float inv1 = powf(10000.f, -(float)(g + 32) / 64.f);
        float cA = cosf(inv0), sA = sinf(inv0);
        float cB = cosf(inv1), sB = sinf(inv1);
        float q1[4] = { q[1][0]*cA - q[1][2]*sA, q[1][1]*cB - q[1][3]*sB,
                        q[1][2]*cA + q[1][0]*sA, q[1][3]*cB + q[1][1]*sB };
        float k1[4] = { k[1][0]*cA - k[1][2]*sA, k[1][1]*cB - k[1][3]*sB,
                        k[1][2]*cA + k[1][0]*sA, k[1][3]*cB + k[1][1]*sB };

        if (task == 0) {
#pragma unroll
            for (int c = 0; c < 4; ++c) {
                int d = g + c * 32;
                kvc[hh * 256 +       d] = k[0][c];
                kvc[hh * 256 + 128 + d] = k1[c];
                kvc[2048 + hh * 256 +       d] = v[0][c];
                kvc[2048 + hh * 256 + 128 + d] = v[1][c];
            }
        }

        float p00 = red32(q[0][0]*k[0][0] + q[0][1]*k[0][1] + q[0][2]*k[0][2] + q[0][3]*k[0][3]);
        float p01 = red32(q[0][0]*k1[0]   + q[0][1]*k1[1]   + q[0][2]*k1[2]   + q[0][3]*k1[3]);
        float p10 = red32(q1[0]*k[0][0]   + q1[1]*k[0][1]   + q1[2]*k[0][2]   + q1[3]*k[0][3]);
        float p11 = red32(q1[0]*k1[0]     + q1[1]*k1[1]     + q1[2]*k1[2]     + q1[3]*k1[3]);

        const float scale = 0.08838834764831845f; // 1/sqrt(128)
        float s00 = p00 * scale, s01 = p01 * scale - 1e9f;
        float m0 = fmaxf(s00, s01);
        float e0 = expf(s00 - m0), e1 = expf(s01 - m0);
        float in0 = 1.f / (e0 + e1);
        float w00 = e0 * in0, w01 = e1 * in0;
        float s10 = p10 * scale, s11 = p11 * scale;
        float m1 = fmaxf(s10, s11);
        float f0 = expf(s10 - m1), f1 = expf(s11 - m1);
        float in1 = 1.f / (f0 + f1);
        float w10 = f0 * in1, w11 = f1 * in1;

#pragma unroll
        for (int c = 0; c < 4; ++c) {
            int d = g + c * 32;
            xs[       hh * 128 + d] = w00 * v[0][c] + w01 * v[1][c];
            xs[1024 + hh * 128 + d] = w10 * v[0][c] + w11 * v[1][c];
        }
        __syncthreads();

        float acc[2][4] = {{0.f,0.f,0.f,0.f},{0.f,0.f,0.f,0.f}};
#pragma unroll
        for (int i = 0; i < 8; ++i) {
            int dd = d0 + i;
#pragma unroll
            for (int s = 0; s < 2; ++s) {
                float xv = xs[s * 1024 + dd];
                acc[s][0] += xv * wreg[i].x; acc[s][1] += xv * wreg[i].y;
                acc[s][2] += xv * wreg[i].z; acc[s][3] += xv * wreg[i].w;
            }
        }
        __syncthreads();
#pragma unroll
        for (int s = 0; s < 2; ++s)
#pragma unroll
            for (int c = 0; c < 4; ++c)
                xs[(dp * 2 + s) * 256 + lane * 4 + c] = acc[s][c];
        __syncthreads();
        for (int o = t; o < 512; o += 256) {
            int s = o >> 8, col = o & 255;
            float sum = 0.f;
#pragma unroll
            for (int p = 0; p < 4; ++p) sum += xs[(p * 2 + s) * 256 + col];
            atomicAdd(out + (size_t)s * 1024 + bx * 256 + col, sum);
        }
        task_done(sync, didx, t);
    }
}

// ---------------- down-proj with fused silu(gate)*up (256 tasks, 64 rows each) ----------------
__device__ void phase_down(
    float* smem, int t,
    const float* __restrict__ gu, const float* __restrict__ W,
    float* __restrict__ hp,
    int* sync, int phase, int widx, int wneed, int didx)
{
    __shared__ int tsk;
    float* red = smem;             // 2048
    float* a   = smem + 2048;      // 2*64
    const int lane = t & 63;
    const int dp = t >> 6;
    bool waited = false;

    while (true) {
        if (t == 0)
            tsk = __hip_atomic_fetch_add(sync + phase * 16, 1, __ATOMIC_RELAXED,
                                         __HIP_MEMORY_SCOPE_AGENT);
        __syncthreads();
        const int task = tsk;
        if (task >= 256) break;

        const int bx = task & 3;
        const int by = task >> 2;     // 64 y-slices of 64 rows
        const int j = bx * 256 + lane * 4;
        const int f0 = by * 64 + dp * 16;
        float* out = hp + (by & 1) * 2048;

        float4 wreg[16];
        const float* Wp = W + (size_t)f0 * 1024 + j;
#pragma unroll
        for (int i = 0; i < 16; ++i)
            wreg[i] = *reinterpret_cast<const float4*>(Wp + (size_t)i * 1024);

        if (!waited) { spin_wait(sync, widx, wneed, t); waited = true; }

        if (t < 128) {
            int s = t >> 6, x = t & 63;
            int f = by * 64 + x;
            float g = ato(gu + s * 8192 + f);
            float u = ato(gu + s * 8192 + 4096 + f);
            a[s * 64 + x] = g / (1.f + expf(-g)) * u;
        }
        __syncthreads();

        float acc[2][4] = {{0.f,0.f,0.f,0.f},{0.f,0.f,0.f,0.f}};
#pragma unroll
        for (int i = 0; i < 16; ++i) {
            int dl = dp * 16 + i;
#pragma unroll
            for (int s = 0; s < 2; ++s) {
                float xv = a[s * 64 + dl];
                acc[s][0] += xv * wreg[i].x; acc[s][1] += xv * wreg[i].y;
                acc[s][2] += xv * wreg[i].z; acc[s][3] += xv * wreg[i].w;
            }
        }
        __syncthreads();
#pragma unroll
        for (int s = 0; s < 2; ++s)
#pragma unroll
            for (int c = 0; c < 4; ++c)
                red[(dp * 2 + s) * 256 + lane * 4 + c] = acc[s][c];
        __syncthreads();
        for (int o = t; o < 512; o += 256) {
            int s = o >> 8, col = o & 255;
            float sum = 0.f;
#pragma unroll
            for (int p = 0; p < 4; ++p) sum += red[(p * 2 + s) * 256 + col];
            atomicAdd(out + (size_t)s * 1024 + bx * 256 + col, sum);
        }
        task_done(sync, didx, t);
    }
}

// ---------------- whole network, persistent kernel, work-stealing flag pipeline ----------------
__global__ __launch_bounds__(256, 4) void net_kernel(
    const float* __restrict__ Wq, const float* __restrict__ Wk,
    const float* __restrict__ Wv, const float* __restrict__ Wo,
    const float* __restrict__ qnw, const float* __restrict__ knw,
    const float* __restrict__ ln1, const float* __restrict__ ln2,
    const float* __restrict__ Wg, const float* __restrict__ Wu,
    const float* __restrict__ Wd, const float* __restrict__ fnw,
    const float* __restrict__ lmh,
    float* __restrict__ ws, float* __restrict__ logits, float* __restrict__ kvc)
{
    __shared__ float smem[2176];
    const int t = threadIdx.x;
    float* h    = ws;
    float* qkvb = ws + 2048;
    float* hp   = ws + HP_OFF;
    float* gub  = ws + 43008;
    int* sync   = (int*)(ws + SYNC_OFF);

    for (int l = 0; l < 5; ++l) {
        const float* wq = Wq + (size_t)l * 1024 * 1024;
        const float* wk = Wk + (size_t)l * 1024 * 1024;
        const float* wv = Wv + (size_t)l * 1024 * 1024;
        const float* wo = Wo + (size_t)l * 1024 * 1024;
        const float* wg = Wg + (size_t)l * 1024 * 4096;
        const float* wu = Wu + (size_t)l * 1024 * 4096;
        const float* wd = Wd + (size_t)l * 4096 * 1024;
        float* qkv = qkvb + l * 6144;
        float* gu  = gub  + l * 16384;

        // QKV (192 tasks, R=16): waits on previous down (256 tasks), none for l=0
        phase_gemv<2, 16>(smem, t, h, hp, ln1 + l * 1024, wq, wk, wv, 0,
                          qkv, 3072, 1024, 1024, 4, 16, 3,
                          sync, 4 * l, l ? 4 * (l - 1) + 3 : -1, 256, 4 * l);
        // attention + O-proj (128 tasks): waits on qkv (192)
        phase_attn_o(smem, t, qkv, qnw + l * 128, knw + l * 128, wo, hp,
                     kvc + (size_t)(2 * l) * 2048,
                     sync, 4 * l + 1, 4 * l, 192, 4 * l + 1);
        // gate & up (512 tasks, R=16): waits on attn_o (128)
        phase_gemv<2, 16>(smem, t, h, hp, ln2 + l * 1024, wg, wu, wu, 0,
                          gu, 8192, 4096, 4096, 16, 16, 2,
                          sync, 4 * l + 2, 4 * l + 1, 128, 4 * l + 2);
        // down proj (256 tasks, R=16): waits on gate/up (512)
        phase_down(smem, t, gu, wd, hp,
                   sync, 4 * l + 3, 4 * l + 2, 512, 4 * l + 3);
    }

    // lm heads + deferred final rmsnorm (1920 tasks, R=16): waits on last down (256)
    phase_gemv<1, 16>(smem, t, h + 1024, hp + 1024, fnw, lmh, nullptr, nullptr,
                      (size_t)1024 * 2048, logits, 2048, 2048, 2048,
                      8, 16, 15, sync, 20, 19, 256, -1);
}

extern "C" void kernel_launch(void* const* d_in, const int* in_sizes, int n_in,
                              void* d_out, int out_size, void* d_ws, size_t ws_size,
                              hipStream_t stream)
{
    const float* past_hidden = (const float*)d_in[0];
    const int*   cb0         = (const int*)d_in[1];
    const float* codec_emb   = (const float*)d_in[2];
    const float* Wq  = (const float*)d_in[3];
    const float* Wk  = (const float*)d_in[4];
    const float* Wv  = (const float*)d_in[5];
    const float* Wo  = (const float*)d_in[6];
    const float* qnw = (const float*)d_in[7];
    const float* knw = (const float*)d_in[8];
    const float* ln1 = (const float*)d_in[9];
    const float* ln2 = (const float*)d_in[10];
    const float* Wg  = (const float*)d_in[11];
    const float* Wu  = (const float*)d_in[12];
    const float* Wd  = (const float*)d_in[13];
    const float* fnw = (const float*)d_in[14];
    const float* lmh = (const float*)d_in[15];

    float* ws     = (float*)d_ws;
    float* logits = (float*)d_out;
    float* kvc    = (float*)d_out + 30720;

    init_kernel<<<128, 256, 0, stream>>>(past_hidden, codec_emb, cb0, ws, logits);

    // Normal launch: work-stealing queues make the schedule deadlock-free for ANY
    // number of resident blocks (each block drains phase queues in program order).
    net_kernel<<<1024, 256, 0, stream>>>(
        Wq, Wk, Wv, Wo, qnw, knw, ln1, ln2, Wg, Wu, Wd, fnw, lmh,
        ws, logits, kvc);
}